// Round 5
// baseline (224.617 us; speedup 1.0000x reference)
//
#include <hip/hip_runtime.h>

// YOLO loss: input [B,30,7,7] f32, target [B,7,7,30] f32 -> scalar f32.
//
// Round 8: cache-policy probe. Five falsified theories (coalescing r4,
// atomic chain r5, MLP/DMA r6, dispatch cost r7, occupancy throughout):
// kernel time is pinned at 70-76us in every configuration = 193 MB
// irreducible reads / ~2.7 TB/s. Cold and L3-warm dispatches take the
// same time; their shared segment is the L3(MALL)->L2 read path.
// Hypothesis: the cap is the L3 allocation/hit machinery, not fabric
// capacity. Probe: non-temporal loads (nt bit -> no MALL allocation,
// HBM->L2 streaming) + contiguous per-block chunks for DRAM locality.
// Predict: dur -> 35-50us, FETCH -> ~190MB, hbm_gbps -> 4+ TB/s.
// If null: declare structural roofline (all mechanism classes probed).

#define NCH    30
#define CELLS  49
#define TPB    256
#define GRID   1024
#define IMGSZ  448.0f
#define CELLSZ 64.0f

typedef float v2f __attribute__((ext_vector_type(2)));

__device__ __forceinline__ float ldnt(const float* p) {
    return __builtin_nontemporal_load(p);
}
__device__ __forceinline__ v2f ldnt2(const float* p) {
    return __builtin_nontemporal_load(reinterpret_cast<const v2f*>(p));
}

__device__ __forceinline__ float iou_f(float ax1, float ay1, float ax2, float ay2,
                                       float bx1, float by1, float bx2, float by2) {
    float l  = fmaxf(ax1, bx1);
    float r  = fminf(ax2, bx2);
    float t  = fmaxf(ay1, by1);
    float bo = fminf(ay2, by2);
    bool  m  = (l < r) && (t < bo);
    float inter = (r - l) * (bo - t);
    float uni   = (ax2 - ax1) * (ay2 - ay1) + (bx2 - bx1) * (by2 - by1);
    float denom = uni - inter;
    return m ? (inter / denom) : 0.0f;
}

__device__ __forceinline__ void decode_box(float p0, float p1, float p2, float p3,
                                           float gx, float gy,
                                           float& x1, float& y1, float& x2, float& y2) {
    float cx = p0 * CELLSZ + gx;
    float cy = p1 * CELLSZ + gy;
    float w  = p2 * IMGSZ;
    float h  = p3 * IMGSZ;
    x1 = fminf(fmaxf(cx - w * 0.5f, 0.0f), IMGSZ);
    y1 = fminf(fmaxf(cy - h * 0.5f, 0.0f), IMGSZ);
    x2 = fminf(fmaxf(cx + w * 0.5f, 0.0f), IMGSZ);
    y2 = fminf(fmaxf(cy + h * 0.5f, 0.0f), IMGSZ);
}

__device__ __forceinline__ float cell_loss(const float* __restrict__ input,
                                           const float* __restrict__ target,
                                           int n) {
    const int b    = n / CELLS;
    const int cell = n - b * CELLS;

    // issue all 45 loads up front, all non-temporal (no L3 allocation)
    const float* __restrict__ tp = target + (size_t)n * NCH;
    const float* __restrict__ ip = input + (size_t)b * (NCH * CELLS) + cell;

    v2f   tv[15];
    float x[NCH];
    #pragma unroll
    for (int k = 0; k < 15; ++k) tv[k] = ldnt2(tp + 2 * k);   // 120B row, 8B aligned
    #pragma unroll
    for (int c = 0; c < NCH; ++c) x[c] = ldnt(ip + c * CELLS);

    float tl[NCH];
    #pragma unroll
    for (int k = 0; k < 15; ++k) { tl[2 * k] = tv[k].x; tl[2 * k + 1] = tv[k].y; }

    const int row  = cell / 7;
    const int col  = cell - row * 7;
    const float gx = (float)col * CELLSZ;
    const float gy = (float)row * CELLSZ;

    float p0x1, p0y1, p0x2, p0y2, p1x1, p1y1, p1x2, p1y2;
    decode_box(x[0], x[1], x[2], x[3], gx, gy, p0x1, p0y1, p0x2, p0y2);
    decode_box(x[5], x[6], x[7], x[8], gx, gy, p1x1, p1y1, p1x2, p1y2);
    float t0x1, t0y1, t0x2, t0y2, t1x1, t1y1, t1x2, t1y2;
    decode_box(tl[0], tl[1], tl[2], tl[3], gx, gy, t0x1, t0y1, t0x2, t0y2);
    decode_box(tl[5], tl[6], tl[7], tl[8], gx, gy, t1x1, t1y1, t1x2, t1y2);

    float iou1 = iou_f(p0x1, p0y1, p0x2, p0y2, t0x1, t0y1, t0x2, t0y2);
    float iou2 = iou_f(p1x1, p1y1, p1x2, p1y2, t1x1, t1y1, t1x2, t1y2);

    bool  mask = iou1 < iou2;
    float iou  = mask ? iou2 : iou1;
    float s0 = mask ? x[5] : x[0];
    float s1 = mask ? x[6] : x[1];
    float s2 = mask ? x[7] : x[2];
    float s3 = mask ? x[8] : x[3];
    float s4 = mask ? x[9] : x[4];

    float w = (tl[4] == 1.0f) ? 1.0f : 0.0f;

    float d0 = s0 - tl[0];
    float d1 = s1 - tl[1];
    float coord = d0 * d0 + d1 * d1;

    float ds2 = sqrtf(s2) - sqrtf(tl[2]);
    float ds3 = sqrtf(s3) - sqrtf(tl[3]);
    float size = ds2 * ds2 + ds3 * ds3;

    float dc = s4 - iou;
    float conf = dc * dc;
    float noobj = s4 * s4;

    float cls = 0.0f;
    #pragma unroll
    for (int c = 10; c < NCH; ++c) {
        float d = x[c] - tl[c];
        cls += d * d;
    }

    return w * (5.0f * (coord + size) + conf + cls) + 0.5f * (1.0f - w) * noobj;
}

template <bool USE_ATOMIC>
__global__ __launch_bounds__(TPB) void yolo_loss_kernel(
        const float* __restrict__ input,   // [B,30,7,7]
        const float* __restrict__ target,  // [B,7,7,30] == [N,30]
        float* __restrict__ dst,           // USE_ATOMIC ? scalar : partials[grid]
        int ncells) {
    __shared__ float red[TPB / 64];

    const int tid = threadIdx.x;
    // contiguous chunk per block: sequential address stream per CU
    const int chunk = (ncells + gridDim.x - 1) / gridDim.x;   // 784
    const int start = blockIdx.x * chunk;
    const int end   = min(start + chunk, ncells);

    float loss = 0.0f;
    for (int n = start + tid; n < end; n += TPB)
        loss += cell_loss(input, target, n);

    #pragma unroll
    for (int off = 32; off > 0; off >>= 1)
        loss += __shfl_down(loss, off, 64);

    const int wid  = tid >> 6;
    const int lane = tid & 63;
    if (lane == 0) red[wid] = loss;
    __syncthreads();
    if (tid == 0) {
        float s = 0.0f;
        #pragma unroll
        for (int i = 0; i < TPB / 64; ++i) s += red[i];
        if (USE_ATOMIC) atomicAdd(dst, s);
        else            dst[blockIdx.x] = s;
    }
}

__global__ __launch_bounds__(TPB) void reduce_kernel(
        const float* __restrict__ parts, float* __restrict__ out, int n) {
    __shared__ float red[TPB / 64];
    float s = 0.0f;
    for (int i = threadIdx.x; i < n; i += TPB) s += parts[i];
    #pragma unroll
    for (int off = 32; off > 0; off >>= 1)
        s += __shfl_down(s, off, 64);
    const int wid  = threadIdx.x >> 6;
    const int lane = threadIdx.x & 63;
    if (lane == 0) red[wid] = s;
    __syncthreads();
    if (threadIdx.x == 0) {
        float t = 0.0f;
        #pragma unroll
        for (int i = 0; i < TPB / 64; ++i) t += red[i];
        *out = t;   // plain store overwrites poison; no memset needed
    }
}

extern "C" void kernel_launch(void* const* d_in, const int* in_sizes, int n_in,
                              void* d_out, int out_size, void* d_ws, size_t ws_size,
                              hipStream_t stream) {
    const float* input  = (const float*)d_in[0];   // [B,30,7,7]
    const float* target = (const float*)d_in[1];   // [B,7,7,30]
    float* out = (float*)d_out;

    const int ncells = in_sizes[0] / NCH;          // B*49 = 802816
    int blocks = (ncells + TPB - 1) / TPB;
    if (blocks > GRID) blocks = GRID;              // chunked above this

    if (d_ws != nullptr && ws_size >= (size_t)blocks * sizeof(float)) {
        float* parts = (float*)d_ws;
        yolo_loss_kernel<false><<<blocks, TPB, 0, stream>>>(input, target, parts, ncells);
        reduce_kernel<<<1, TPB, 0, stream>>>(parts, out, blocks);
    } else {
        hipMemsetAsync(d_out, 0, sizeof(float), stream);
        yolo_loss_kernel<true><<<blocks, TPB, 0, stream>>>(input, target, out, ncells);
    }
}

// Round 6
// 204.488 us; speedup vs baseline: 1.0984x; 1.0984x over previous
//
#include <hip/hip_runtime.h>

// YOLO loss: input [B,30,7,7] f32, target [B,7,7,30] f32 -> scalar f32.
//
// Round 9: REVERT to the empirically best configuration (round-0 kernel,
// score 204.1/204.27, kernel 71.1us). Rationale: six falsified mechanism
// theories (coalescing r4, atomic chain r5, MLP/DMA r6, dispatch cost r7,
// occupancy sweep, cache policy r8) — kernel time pinned at 70-76us
// = 193 MB / ~2.7 TB/s regardless of structure, consistent with a per-CU
// outstanding-miss queue limit (~64-80 lines x ~1100cyc = ~4.5 B/cyc/CU).
// r8's NT loads additionally regressed the SCORE (+20us) by deallocating
// input lines from L3, slowing the harness's timed restore-writes.
// This config: allocating loads (L3-friendly for the harness restore),
// minimal dispatch count (memset + 1 kernel), tight 71us kernel.

#define NCH   30
#define CELLS 49
#define TPB   256
#define IMGSZ 448.0f
#define CELLSZ 64.0f

__device__ __forceinline__ float iou_f(float ax1, float ay1, float ax2, float ay2,
                                       float bx1, float by1, float bx2, float by2) {
    float l  = fmaxf(ax1, bx1);
    float r  = fminf(ax2, bx2);
    float t  = fmaxf(ay1, by1);
    float bo = fminf(ay2, by2);
    bool  m  = (l < r) && (t < bo);
    float inter = (r - l) * (bo - t);
    float uni   = (ax2 - ax1) * (ay2 - ay1) + (bx2 - bx1) * (by2 - by1);
    float denom = uni - inter;
    return m ? (inter / denom) : 0.0f;
}

__device__ __forceinline__ void decode_box(float p0, float p1, float p2, float p3,
                                           float gx, float gy,
                                           float& x1, float& y1, float& x2, float& y2) {
    float cx = p0 * CELLSZ + gx;
    float cy = p1 * CELLSZ + gy;
    float w  = p2 * IMGSZ;
    float h  = p3 * IMGSZ;
    x1 = fminf(fmaxf(cx - w * 0.5f, 0.0f), IMGSZ);
    y1 = fminf(fmaxf(cy - h * 0.5f, 0.0f), IMGSZ);
    x2 = fminf(fmaxf(cx + w * 0.5f, 0.0f), IMGSZ);
    y2 = fminf(fmaxf(cy + h * 0.5f, 0.0f), IMGSZ);
}

// 4 waves/EU target -> <=128 VGPR/wave, 16 waves/CU (matches measured occupancy)
__global__ __launch_bounds__(TPB, 4) void yolo_loss_kernel(
        const float* __restrict__ input,   // [B,30,7,7]
        const float* __restrict__ target,  // [B,7,7,30] == [N,30]
        float* __restrict__ out,
        int ncells) {
    __shared__ float red[TPB / 64];

    const int tid = threadIdx.x;
    const int n   = blockIdx.x * TPB + tid;

    float loss = 0.0f;
    if (n < ncells) {
        const int b    = n / CELLS;
        const int cell = n - b * CELLS;

        // ---- issue ALL 45 loads before any consumption ----
        const float2* __restrict__ tp =
            reinterpret_cast<const float2*>(target) + (long long)n * 15;
        const float* __restrict__ ip = input + b * (NCH * CELLS) + cell;

        float2 tv[15];
        float  x[NCH];
        #pragma unroll
        for (int k = 0; k < 15; ++k) tv[k] = tp[k];
        #pragma unroll
        for (int c = 0; c < NCH; ++c) x[c] = ip[c * CELLS];

        float tl[NCH];
        #pragma unroll
        for (int k = 0; k < 15; ++k) { tl[2 * k] = tv[k].x; tl[2 * k + 1] = tv[k].y; }

        const int row  = cell / 7;
        const int col  = cell - row * 7;
        const float gx = (float)col * CELLSZ;
        const float gy = (float)row * CELLSZ;

        float p0x1, p0y1, p0x2, p0y2, p1x1, p1y1, p1x2, p1y2;
        decode_box(x[0], x[1], x[2], x[3], gx, gy, p0x1, p0y1, p0x2, p0y2);
        decode_box(x[5], x[6], x[7], x[8], gx, gy, p1x1, p1y1, p1x2, p1y2);
        float t0x1, t0y1, t0x2, t0y2, t1x1, t1y1, t1x2, t1y2;
        decode_box(tl[0], tl[1], tl[2], tl[3], gx, gy, t0x1, t0y1, t0x2, t0y2);
        decode_box(tl[5], tl[6], tl[7], tl[8], gx, gy, t1x1, t1y1, t1x2, t1y2);

        float iou1 = iou_f(p0x1, p0y1, p0x2, p0y2, t0x1, t0y1, t0x2, t0y2);
        float iou2 = iou_f(p1x1, p1y1, p1x2, p1y2, t1x1, t1y1, t1x2, t1y2);

        bool  mask = iou1 < iou2;
        float iou  = mask ? iou2 : iou1;
        float s0 = mask ? x[5] : x[0];
        float s1 = mask ? x[6] : x[1];
        float s2 = mask ? x[7] : x[2];
        float s3 = mask ? x[8] : x[3];
        float s4 = mask ? x[9] : x[4];

        float w = (tl[4] == 1.0f) ? 1.0f : 0.0f;

        float d0 = s0 - tl[0];
        float d1 = s1 - tl[1];
        float coord = d0 * d0 + d1 * d1;

        float ds2 = sqrtf(s2) - sqrtf(tl[2]);
        float ds3 = sqrtf(s3) - sqrtf(tl[3]);
        float size = ds2 * ds2 + ds3 * ds3;

        float dc = s4 - iou;
        float conf = dc * dc;
        float noobj = s4 * s4;

        float cls = 0.0f;
        #pragma unroll
        for (int c = 10; c < NCH; ++c) {
            float d = x[c] - tl[c];
            cls += d * d;
        }

        loss = w * (5.0f * (coord + size) + conf + cls) + 0.5f * (1.0f - w) * noobj;
    }

    // Wave reduce (64 lanes), then block reduce, one atomic per block.
    #pragma unroll
    for (int off = 32; off > 0; off >>= 1)
        loss += __shfl_down(loss, off, 64);

    const int wid  = tid >> 6;
    const int lane = tid & 63;
    if (lane == 0) red[wid] = loss;
    __syncthreads();
    if (tid == 0) {
        float s = 0.0f;
        #pragma unroll
        for (int i = 0; i < TPB / 64; ++i) s += red[i];
        atomicAdd(out, s);
    }
}

extern "C" void kernel_launch(void* const* d_in, const int* in_sizes, int n_in,
                              void* d_out, int out_size, void* d_ws, size_t ws_size,
                              hipStream_t stream) {
    const float* input  = (const float*)d_in[0];   // [B,30,7,7]
    const float* target = (const float*)d_in[1];   // [B,7,7,30]
    float* out = (float*)d_out;

    const int ncells = in_sizes[0] / NCH;          // B*49 = 802816
    const int blocks = (ncells + TPB - 1) / TPB;   // 3136

    // d_out is poisoned 0xAA before every timed launch -> zero it (capture-safe).
    hipMemsetAsync(d_out, 0, sizeof(float), stream);
    yolo_loss_kernel<<<blocks, TPB, 0, stream>>>(input, target, out, ncells);
}